// Round 11
// baseline (46.386 us; speedup 1.0000x reference)
//
#include <hip/hip_runtime.h>
#include <math.h>

#define NHEADS 32
#define NKV 8
#define HD 128
#define DIM 4096
#define KV_DIM 1024
#define SEQ 4096
#define POS 4095
#define NCHUNK 128    // chunks over sequence (1024 blocks = 4/CU)
#define CHUNK 32      // positions per block (4 waves x 8)
#define PPOS 8        // positions per wave (2 looped clumps of 4)

// ws layout (floats):
#define WS_QROT   0                       // [4096]
#define WS_KNEW   4096                    // [1024]
#define WS_VNEW   5120                    // [1024]
#define WS_ACCS   6144                    // [4096]  attn numerator (atomic)
#define WS_LSUM   10240                   // [32]    attn denominator (atomic)

__device__ __forceinline__ float dot4(float4 a, float4 b) {
    return a.x * b.x + a.y * b.y + a.z * b.z + a.w * b.w;
}

// x += perm(x) via DPP. 0xB1=quad_perm xor1, 0x4E=quad_perm xor2,
// 0x124=row_ror:4, 0x128=row_ror:8 -> allreduce-sum per 16-lane row.
template <int CTRL>
__device__ __forceinline__ float dppadd(float x) {
    return x + __int_as_float(__builtin_amdgcn_update_dpp(
        0, __float_as_int(x), CTRL, 0xF, 0xF, true));
}

// ---------------- QKV matvec + fused RoPE (+ accumulator zero-init) --------
// 768 blocks x 256 threads; one wave per EVEN/ODD row pair (2 rows/wave).
// R6-validated structure: stage x -> LDS, sync, THEN the 16-float4 weight
// volley (compiler keeps the volley clumped only in this order).
__global__ __launch_bounds__(256) void qkv_kernel(
    const float* __restrict__ x,
    const float* __restrict__ wq, const float* __restrict__ wk,
    const float* __restrict__ wv,
    const float* __restrict__ fc, const float* __restrict__ fs,
    float* __restrict__ ws)
{
    // zero the attn accumulators for this call (stream order protects vs attn)
    if (blockIdx.x < 16) {
        ws[WS_ACCS + blockIdx.x * 256 + threadIdx.x] = 0.f;
        if (blockIdx.x == 0 && threadIdx.x < NHEADS) ws[WS_LSUM + threadIdx.x] = 0.f;
    }

    __shared__ float xs[DIM];               // 16 KB
    {
        const float4* x4 = (const float4*)x;
        float4* xs4 = (float4*)xs;
        #pragma unroll
        for (int u = 0; u < 4; ++u)
            xs4[u * 256 + threadIdx.x] = x4[u * 256 + threadIdx.x];
    }
    __syncthreads();

    const int wave = threadIdx.x >> 6;
    const int lane = threadIdx.x & 63;
    const int row0 = (blockIdx.x * 4 + wave) * 2;   // even row of the pair

    const float4* xs4 = (const float4*)xs;
    float res[2];
    #pragma unroll
    for (int r = 0; r < 2; ++r) {
        const int row = row0 + r;
        const float* wrow;
        if (row < DIM)               wrow = wq + (size_t)row * DIM;
        else if (row < DIM + KV_DIM) wrow = wk + (size_t)(row - DIM) * DIM;
        else                         wrow = wv + (size_t)(row - DIM - KV_DIM) * DIM;
        const float4* w4 = (const float4*)wrow;

        float4 wb[16];
        #pragma unroll
        for (int u = 0; u < 16; ++u) wb[u] = w4[u * 64 + lane];

        float acc = 0.f;
        #pragma unroll
        for (int u = 0; u < 16; ++u) acc += dot4(wb[u], xs4[u * 64 + lane]);

        #pragma unroll
        for (int off = 32; off; off >>= 1) acc += __shfl_xor(acc, off);
        res[r] = acc;
    }

    if (lane == 0) {
        if (row0 < DIM + KV_DIM) {
            const int p = (row0 & (HD - 1)) >> 1;     // RoPE pair index
            const float c = fc[POS * (HD / 2) + p];
            const float s = fs[POS * (HD / 2) + p];
            ws[row0]     = res[0] * c - res[1] * s;
            ws[row0 + 1] = res[0] * s + res[1] * c;
        } else {
            ws[row0]     = res[0];
            ws[row0 + 1] = res[1];
        }
    }
}

// ---------------- flash-decode partials, atomic combine ----------------
// grid (NCHUNK=128, NKV=8) x 256 threads = 1024 blocks (4/CU). R6-validated
// LOOPED double-buffer structure (4-position clumps, 8 loads in flight);
// only the trip count changed (2 iters vs 4). No min-waves launch_bounds —
// that's what spilled in R8. Fixed-offset softmax p=exp(score-8): linear
// partials -> atomic combine.
__global__ __launch_bounds__(256) void attn_partial(
    const float* __restrict__ kbuf, const float* __restrict__ vbuf,
    float* __restrict__ ws)
{
    const float* qrot = ws + WS_QROT;
    const float* knew = ws + WS_KNEW;
    const float* vnew = ws + WS_VNEW;
    float* accs = ws + WS_ACCS;
    float* lsg  = ws + WS_LSUM;

    const int g     = blockIdx.y;
    const int chunk = blockIdx.x;
    const int wave  = threadIdx.x >> 6;
    const int lane  = threadIdx.x & 63;
    const int qg    = lane >> 4;            // quarter-group: position in clump
    const int ql    = lane & 15;            // float4 slice within row
    const int s0    = chunk * CHUNK + wave * PPOS;

    float4 q0[4], q1[4];
    #pragma unroll
    for (int h = 0; h < 4; ++h) {
        const float4* qb = (const float4*)(qrot + (size_t)(4 * g + h) * HD);
        q0[h] = qb[ql];
        q1[h] = qb[ql + 16];
    }

    const float scale = 0.08838834764831845f;   // 1/sqrt(128)
    float lsum[4] = {0.f, 0.f, 0.f, 0.f};
    float4 acc0[4] = {}, acc1[4] = {};

    float4 kb0[2], kb1[2], vb0[2], vb1[2];
    {
        const int s = s0 + qg;
        const float* kr = (s == POS) ? (knew + g * HD) : (kbuf + ((size_t)g * SEQ + s) * HD);
        const float* vr = (s == POS) ? (vnew + g * HD) : (vbuf + ((size_t)g * SEQ + s) * HD);
        kb0[0] = ((const float4*)kr)[ql]; kb1[0] = ((const float4*)kr)[ql + 16];
        vb0[0] = ((const float4*)vr)[ql]; vb1[0] = ((const float4*)vr)[ql + 16];
    }

    #pragma unroll
    for (int it = 0; it < PPOS / 4; ++it) {     // 2 iters, 4 positions each
        if (it + 1 < PPOS / 4) {
            const int s = s0 + (it + 1) * 4 + qg;
            const float* kr = (s == POS) ? (knew + g * HD) : (kbuf + ((size_t)g * SEQ + s) * HD);
            const float* vr = (s == POS) ? (vnew + g * HD) : (vbuf + ((size_t)g * SEQ + s) * HD);
            const int nb = (it + 1) & 1;
            kb0[nb] = ((const float4*)kr)[ql]; kb1[nb] = ((const float4*)kr)[ql + 16];
            vb0[nb] = ((const float4*)vr)[ql]; vb1[nb] = ((const float4*)vr)[ql + 16];
        }
        const int b = it & 1;

        float d[4];
        #pragma unroll
        for (int h = 0; h < 4; ++h)
            d[h] = dot4(kb0[b], q0[h]) + dot4(kb1[b], q1[h]);

        #pragma unroll
        for (int h = 0; h < 4; ++h) {
            d[h] = dppadd<0xB1>(d[h]);      // xor 1 (quad_perm)
            d[h] = dppadd<0x4E>(d[h]);      // xor 2 (quad_perm)
            d[h] = dppadd<0x124>(d[h]);     // row_ror:4
            d[h] = dppadd<0x128>(d[h]);     // row_ror:8
        }

        #pragma unroll
        for (int h = 0; h < 4; ++h) {
            const float p = __expf(d[h] * scale - 8.0f);
            lsum[h] += p;
            acc0[h].x += p * vb0[b].x;
            acc0[h].y += p * vb0[b].y;
            acc0[h].z += p * vb0[b].z;
            acc0[h].w += p * vb0[b].w;
            acc1[h].x += p * vb1[b].x;
            acc1[h].y += p * vb1[b].y;
            acc1[h].z += p * vb1[b].z;
            acc1[h].w += p * vb1[b].w;
        }
    }

    // merge the 4 quarter-group partials (once per wave; pure adds)
    #pragma unroll
    for (int h = 0; h < 4; ++h) {
        lsum[h] += __shfl_xor(lsum[h], 16);
        lsum[h] += __shfl_xor(lsum[h], 32);
        acc0[h].x += __shfl_xor(acc0[h].x, 16); acc0[h].x += __shfl_xor(acc0[h].x, 32);
        acc0[h].y += __shfl_xor(acc0[h].y, 16); acc0[h].y += __shfl_xor(acc0[h].y, 32);
        acc0[h].z += __shfl_xor(acc0[h].z, 16); acc0[h].z += __shfl_xor(acc0[h].z, 32);
        acc0[h].w += __shfl_xor(acc0[h].w, 16); acc0[h].w += __shfl_xor(acc0[h].w, 32);
        acc1[h].x += __shfl_xor(acc1[h].x, 16); acc1[h].x += __shfl_xor(acc1[h].x, 32);
        acc1[h].y += __shfl_xor(acc1[h].y, 16); acc1[h].y += __shfl_xor(acc1[h].y, 32);
        acc1[h].z += __shfl_xor(acc1[h].z, 16); acc1[h].z += __shfl_xor(acc1[h].z, 32);
        acc1[h].w += __shfl_xor(acc1[h].w, 16); acc1[h].w += __shfl_xor(acc1[h].w, 32);
    }

    // deterministic wave merge in LDS, then atomic combine
    __shared__ float sacc[4][4][HD];    // 8 KB
    __shared__ float sl[4][4];
    if (qg == 0) {
        #pragma unroll
        for (int h = 0; h < 4; ++h) {
            ((float4*)sacc[wave][h])[ql]      = acc0[h];
            ((float4*)sacc[wave][h])[ql + 16] = acc1[h];
        }
    }
    if (lane == 0) {
        #pragma unroll
        for (int h = 0; h < 4; ++h) sl[wave][h] = lsum[h];
    }
    __syncthreads();

    for (int idx = threadIdx.x; idx < 4 * HD; idx += 256) {
        const int h = idx >> 7, j = idx & (HD - 1);
        const float sv = sacc[0][h][j] + sacc[1][h][j] + sacc[2][h][j] + sacc[3][h][j];
        atomicAdd(&accs[(4 * g + h) * HD + j], sv);
    }
    if (threadIdx.x < 4) {
        const int h = threadIdx.x;
        atomicAdd(&lsg[4 * g + h], sl[0][h] + sl[1][h] + sl[2][h] + sl[3][h]);
    }
}

// ---------------- output projection (normalizes inline) ----------------
// 1024 blocks x 256 threads; one wave per row; R6-validated order:
// stage normalized accs -> LDS, sync, THEN the wo volley.
__global__ __launch_bounds__(256) void out_kernel(
    const float* __restrict__ wo, const float* __restrict__ ws,
    float* __restrict__ out)
{
    __shared__ float as[DIM];               // 16 KB
    __shared__ float sinv[NHEADS];

    if (threadIdx.x < NHEADS)
        sinv[threadIdx.x] = 1.f / ws[WS_LSUM + threadIdx.x];
    __syncthreads();

    {
        const float4* a4 = (const float4*)(ws + WS_ACCS);
        float4* as4 = (float4*)as;
        #pragma unroll
        for (int u = 0; u < 4; ++u) {
            const int j4 = u * 256 + threadIdx.x;     // float4 idx; head = j4>>5
            float4 v = a4[j4];
            const float iv = sinv[j4 >> 5];
            v.x *= iv; v.y *= iv; v.z *= iv; v.w *= iv;
            as4[j4] = v;
        }
    }
    __syncthreads();

    const int wave = threadIdx.x >> 6;
    const int lane = threadIdx.x & 63;
    const int row  = blockIdx.x * 4 + wave;

    const float4* w4  = (const float4*)(wo + (size_t)row * DIM);
    const float4* as4 = (const float4*)as;

    float4 wb[16];
    #pragma unroll
    for (int u = 0; u < 16; ++u) wb[u] = w4[u * 64 + lane];

    float acc = 0.f;
    #pragma unroll
    for (int u = 0; u < 16; ++u) acc += dot4(wb[u], as4[u * 64 + lane]);

    #pragma unroll
    for (int off = 32; off; off >>= 1) acc += __shfl_xor(acc, off);
    if (lane == 0) out[row] = acc;
}

extern "C" void kernel_launch(void* const* d_in, const int* in_sizes, int n_in,
                              void* d_out, int out_size, void* d_ws, size_t ws_size,
                              hipStream_t stream)
{
    const float* x    = (const float*)d_in[0];
    const float* fc   = (const float*)d_in[1];
    const float* fs   = (const float*)d_in[2];
    const float* kbuf = (const float*)d_in[3];
    const float* vbuf = (const float*)d_in[4];
    const float* wq   = (const float*)d_in[5];
    const float* wk   = (const float*)d_in[6];
    const float* wv   = (const float*)d_in[7];
    const float* wo   = (const float*)d_in[8];

    float* ws  = (float*)d_ws;
    float* out = (float*)d_out;

    qkv_kernel<<<(DIM + 2 * KV_DIM) / 8, 256, 0, stream>>>(x, wq, wk, wv, fc, fs, ws);
    attn_partial<<<dim3(NCHUNK, NKV), 256, 0, stream>>>(kbuf, vbuf, ws);
    out_kernel<<<DIM / 4, 256, 0, stream>>>(wo, ws, out);
}

// Round 12
// 42.721 us; speedup vs baseline: 1.0858x; 1.0858x over previous
//
#include <hip/hip_runtime.h>
#include <math.h>

#define NHEADS 32
#define NKV 8
#define HD 128
#define DIM 4096
#define KV_DIM 1024
#define SEQ 4096
#define POS 4095
#define NCHUNK 64     // chunks over sequence
#define CHUNK 64      // positions per block (4 waves x 16)
#define PPOS 16       // positions per wave

// ws layout (floats):
#define WS_QROT   0                       // [4096]
#define WS_KNEW   4096                    // [1024]
#define WS_VNEW   5120                    // [1024]
#define WS_ACCS   6144                    // [4096]  attn numerator (atomic)
#define WS_LSUM   10240                   // [32]    attn denominator (atomic)

__device__ __forceinline__ float dot4(float4 a, float4 b) {
    return a.x * b.x + a.y * b.y + a.z * b.z + a.w * b.w;
}

// x += perm(x) via DPP. 0xB1=quad_perm xor1, 0x4E=quad_perm xor2,
// 0x124=row_ror:4, 0x128=row_ror:8 -> allreduce-sum per 16-lane row.
template <int CTRL>
__device__ __forceinline__ float dppadd(float x) {
    return x + __int_as_float(__builtin_amdgcn_update_dpp(
        0, __float_as_int(x), CTRL, 0xF, 0xF, true));
}

// ---------------- QKV matvec + fused RoPE (+ accumulator zero-init) --------
// 768 blocks x 256 threads; one wave per EVEN/ODD row pair (2 rows/wave).
// R6-validated structure: stage x -> LDS, sync, THEN the 16-float4 weight
// volley (compiler keeps the volley clumped only in this order).
__global__ __launch_bounds__(256) void qkv_kernel(
    const float* __restrict__ x,
    const float* __restrict__ wq, const float* __restrict__ wk,
    const float* __restrict__ wv,
    const float* __restrict__ fc, const float* __restrict__ fs,
    float* __restrict__ ws)
{
    // zero the attn accumulators for this call (stream order protects vs attn)
    if (blockIdx.x < 16) {
        ws[WS_ACCS + blockIdx.x * 256 + threadIdx.x] = 0.f;
        if (blockIdx.x == 0 && threadIdx.x < NHEADS) ws[WS_LSUM + threadIdx.x] = 0.f;
    }

    __shared__ float xs[DIM];               // 16 KB
    {
        const float4* x4 = (const float4*)x;
        float4* xs4 = (float4*)xs;
        #pragma unroll
        for (int u = 0; u < 4; ++u)
            xs4[u * 256 + threadIdx.x] = x4[u * 256 + threadIdx.x];
    }
    __syncthreads();

    const int wave = threadIdx.x >> 6;
    const int lane = threadIdx.x & 63;
    const int row0 = (blockIdx.x * 4 + wave) * 2;   // even row of the pair

    const float4* xs4 = (const float4*)xs;
    float res[2];
    #pragma unroll
    for (int r = 0; r < 2; ++r) {
        const int row = row0 + r;
        const float* wrow;
        if (row < DIM)               wrow = wq + (size_t)row * DIM;
        else if (row < DIM + KV_DIM) wrow = wk + (size_t)(row - DIM) * DIM;
        else                         wrow = wv + (size_t)(row - DIM - KV_DIM) * DIM;
        const float4* w4 = (const float4*)wrow;

        float4 wb[16];
        #pragma unroll
        for (int u = 0; u < 16; ++u) wb[u] = w4[u * 64 + lane];

        float acc = 0.f;
        #pragma unroll
        for (int u = 0; u < 16; ++u) acc += dot4(wb[u], xs4[u * 64 + lane]);

        #pragma unroll
        for (int off = 32; off; off >>= 1) acc += __shfl_xor(acc, off);
        res[r] = acc;
    }

    if (lane == 0) {
        if (row0 < DIM + KV_DIM) {
            const int p = (row0 & (HD - 1)) >> 1;     // RoPE pair index
            const float c = fc[POS * (HD / 2) + p];
            const float s = fs[POS * (HD / 2) + p];
            ws[row0]     = res[0] * c - res[1] * s;
            ws[row0 + 1] = res[0] * s + res[1] * c;
        } else {
            ws[row0]     = res[0];
            ws[row0 + 1] = res[1];
        }
    }
}

// ---------------- flash-decode partials, atomic combine ----------------
// grid (NCHUNK=64, NKV=8) x 256 threads. Quarter-wave layout + DPP reduce
// (validated R4). Looped double-buffer (4-position clumps, 8 loads in
// flight) — R6-validated best. NCHUNK=128 variant regressed (R11: heavier
// per-block epilogue dominated). Fixed-offset softmax p = exp(score-8):
// linear partials -> atomic combine.
__global__ __launch_bounds__(256) void attn_partial(
    const float* __restrict__ kbuf, const float* __restrict__ vbuf,
    float* __restrict__ ws)
{
    const float* qrot = ws + WS_QROT;
    const float* knew = ws + WS_KNEW;
    const float* vnew = ws + WS_VNEW;
    float* accs = ws + WS_ACCS;
    float* lsg  = ws + WS_LSUM;

    const int g     = blockIdx.y;
    const int chunk = blockIdx.x;
    const int wave  = threadIdx.x >> 6;
    const int lane  = threadIdx.x & 63;
    const int qg    = lane >> 4;            // quarter-group: position in clump
    const int ql    = lane & 15;            // float4 slice within row
    const int s0    = chunk * CHUNK + wave * PPOS;

    float4 q0[4], q1[4];
    #pragma unroll
    for (int h = 0; h < 4; ++h) {
        const float4* qb = (const float4*)(qrot + (size_t)(4 * g + h) * HD);
        q0[h] = qb[ql];
        q1[h] = qb[ql + 16];
    }

    const float scale = 0.08838834764831845f;   // 1/sqrt(128)
    float lsum[4] = {0.f, 0.f, 0.f, 0.f};
    float4 acc0[4] = {}, acc1[4] = {};

    float4 kb0[2], kb1[2], vb0[2], vb1[2];
    {
        const int s = s0 + qg;
        const float* kr = (s == POS) ? (knew + g * HD) : (kbuf + ((size_t)g * SEQ + s) * HD);
        const float* vr = (s == POS) ? (vnew + g * HD) : (vbuf + ((size_t)g * SEQ + s) * HD);
        kb0[0] = ((const float4*)kr)[ql]; kb1[0] = ((const float4*)kr)[ql + 16];
        vb0[0] = ((const float4*)vr)[ql]; vb1[0] = ((const float4*)vr)[ql + 16];
    }

    #pragma unroll
    for (int it = 0; it < PPOS / 4; ++it) {     // 4 iters, 4 positions each
        if (it + 1 < PPOS / 4) {
            const int s = s0 + (it + 1) * 4 + qg;
            const float* kr = (s == POS) ? (knew + g * HD) : (kbuf + ((size_t)g * SEQ + s) * HD);
            const float* vr = (s == POS) ? (vnew + g * HD) : (vbuf + ((size_t)g * SEQ + s) * HD);
            const int nb = (it + 1) & 1;
            kb0[nb] = ((const float4*)kr)[ql]; kb1[nb] = ((const float4*)kr)[ql + 16];
            vb0[nb] = ((const float4*)vr)[ql]; vb1[nb] = ((const float4*)vr)[ql + 16];
        }
        const int b = it & 1;

        float d[4];
        #pragma unroll
        for (int h = 0; h < 4; ++h)
            d[h] = dot4(kb0[b], q0[h]) + dot4(kb1[b], q1[h]);

        #pragma unroll
        for (int h = 0; h < 4; ++h) {
            d[h] = dppadd<0xB1>(d[h]);      // xor 1 (quad_perm)
            d[h] = dppadd<0x4E>(d[h]);      // xor 2 (quad_perm)
            d[h] = dppadd<0x124>(d[h]);     // row_ror:4
            d[h] = dppadd<0x128>(d[h]);     // row_ror:8
        }

        #pragma unroll
        for (int h = 0; h < 4; ++h) {
            const float p = __expf(d[h] * scale - 8.0f);
            lsum[h] += p;
            acc0[h].x += p * vb0[b].x;
            acc0[h].y += p * vb0[b].y;
            acc0[h].z += p * vb0[b].z;
            acc0[h].w += p * vb0[b].w;
            acc1[h].x += p * vb1[b].x;
            acc1[h].y += p * vb1[b].y;
            acc1[h].z += p * vb1[b].z;
            acc1[h].w += p * vb1[b].w;
        }
    }

    // merge the 4 quarter-group partials (once per wave; pure adds)
    #pragma unroll
    for (int h = 0; h < 4; ++h) {
        lsum[h] += __shfl_xor(lsum[h], 16);
        lsum[h] += __shfl_xor(lsum[h], 32);
        acc0[h].x += __shfl_xor(acc0[h].x, 16); acc0[h].x += __shfl_xor(acc0[h].x, 32);
        acc0[h].y += __shfl_xor(acc0[h].y, 16); acc0[h].y += __shfl_xor(acc0[h].y, 32);
        acc0[h].z += __shfl_xor(acc0[h].z, 16); acc0[h].z += __shfl_xor(acc0[h].z, 32);
        acc0[h].w += __shfl_xor(acc0[h].w, 16); acc0[h].w += __shfl_xor(acc0[h].w, 32);
        acc1[h].x += __shfl_xor(acc1[h].x, 16); acc1[h].x += __shfl_xor(acc1[h].x, 32);
        acc1[h].y += __shfl_xor(acc1[h].y, 16); acc1[h].y += __shfl_xor(acc1[h].y, 32);
        acc1[h].z += __shfl_xor(acc1[h].z, 16); acc1[h].z += __shfl_xor(acc1[h].z, 32);
        acc1[h].w += __shfl_xor(acc1[h].w, 16); acc1[h].w += __shfl_xor(acc1[h].w, 32);
    }

    // deterministic wave merge in LDS, then atomic combine
    __shared__ float sacc[4][4][HD];    // 8 KB
    __shared__ float sl[4][4];
    if (qg == 0) {
        #pragma unroll
        for (int h = 0; h < 4; ++h) {
            ((float4*)sacc[wave][h])[ql]      = acc0[h];
            ((float4*)sacc[wave][h])[ql + 16] = acc1[h];
        }
    }
    if (lane == 0) {
        #pragma unroll
        for (int h = 0; h < 4; ++h) sl[wave][h] = lsum[h];
    }
    __syncthreads();

    for (int idx = threadIdx.x; idx < 4 * HD; idx += 256) {
        const int h = idx >> 7, j = idx & (HD - 1);
        const float sv = sacc[0][h][j] + sacc[1][h][j] + sacc[2][h][j] + sacc[3][h][j];
        atomicAdd(&accs[(4 * g + h) * HD + j], sv);
    }
    if (threadIdx.x < 4) {
        const int h = threadIdx.x;
        atomicAdd(&lsg[4 * g + h], sl[0][h] + sl[1][h] + sl[2][h] + sl[3][h]);
    }
}

// ---------------- output projection (normalizes inline) ----------------
// 1024 blocks x 256 threads; one wave per row; R6-validated order:
// stage normalized accs -> LDS, sync, THEN the wo volley.
__global__ __launch_bounds__(256) void out_kernel(
    const float* __restrict__ wo, const float* __restrict__ ws,
    float* __restrict__ out)
{
    __shared__ float as[DIM];               // 16 KB
    __shared__ float sinv[NHEADS];

    if (threadIdx.x < NHEADS)
        sinv[threadIdx.x] = 1.f / ws[WS_LSUM + threadIdx.x];
    __syncthreads();

    {
        const float4* a4 = (const float4*)(ws + WS_ACCS);
        float4* as4 = (float4*)as;
        #pragma unroll
        for (int u = 0; u < 4; ++u) {
            const int j4 = u * 256 + threadIdx.x;     // float4 idx; head = j4>>5
            float4 v = a4[j4];
            const float iv = sinv[j4 >> 5];
            v.x *= iv; v.y *= iv; v.z *= iv; v.w *= iv;
            as4[j4] = v;
        }
    }
    __syncthreads();

    const int wave = threadIdx.x >> 6;
    const int lane = threadIdx.x & 63;
    const int row  = blockIdx.x * 4 + wave;

    const float4* w4  = (const float4*)(wo + (size_t)row * DIM);
    const float4* as4 = (const float4*)as;

    float4 wb[16];
    #pragma unroll
    for (int u = 0; u < 16; ++u) wb[u] = w4[u * 64 + lane];

    float acc = 0.f;
    #pragma unroll
    for (int u = 0; u < 16; ++u) acc += dot4(wb[u], as4[u * 64 + lane]);

    #pragma unroll
    for (int off = 32; off; off >>= 1) acc += __shfl_xor(acc, off);
    if (lane == 0) out[row] = acc;
}

extern "C" void kernel_launch(void* const* d_in, const int* in_sizes, int n_in,
                              void* d_out, int out_size, void* d_ws, size_t ws_size,
                              hipStream_t stream)
{
    const float* x    = (const float*)d_in[0];
    const float* fc   = (const float*)d_in[1];
    const float* fs   = (const float*)d_in[2];
    const float* kbuf = (const float*)d_in[3];
    const float* vbuf = (const float*)d_in[4];
    const float* wq   = (const float*)d_in[5];
    const float* wk   = (const float*)d_in[6];
    const float* wv   = (const float*)d_in[7];
    const float* wo   = (const float*)d_in[8];

    float* ws  = (float*)d_ws;
    float* out = (float*)d_out;

    qkv_kernel<<<(DIM + 2 * KV_DIM) / 8, 256, 0, stream>>>(x, wq, wk, wv, fc, fs, ws);
    attn_partial<<<dim3(NCHUNK, NKV), 256, 0, stream>>>(kbuf, vbuf, ws);
    out_kernel<<<DIM / 4, 256, 0, stream>>>(wo, ws, out);
}